// Round 5
// baseline (394.635 us; speedup 1.0000x reference)
//
#include <hip/hip_runtime.h>
#include <stdint.h>

#define N_NODES 100000
#define N_EDGES 1000000
#define IN_F 128
#define OUT_F 128
#define NUM_RELS 64
#define NB_SCAN ((N_NODES + 255) / 256)   // 391 blocks for the scan

typedef _Float16 half2v __attribute__((ext_vector_type(2)));

__device__ __forceinline__ float dot2f(uint32_t hu, uint32_t wu, float acc) {
#if __has_builtin(__builtin_amdgcn_fdot2)
    return __builtin_amdgcn_fdot2(__builtin_bit_cast(half2v, hu),
                                  __builtin_bit_cast(half2v, wu), acc, false);
#else
    half2v a = __builtin_bit_cast(half2v, hu);
    half2v b = __builtin_bit_cast(half2v, wu);
    acc = fmaf((float)a.x, (float)b.x, acc);
    acc = fmaf((float)a.y, (float)b.y, acc);
    return acc;
#endif
}

// ---------------------------------------------------------------------------
// Kernel A: out[n][o] = bias[o] + sum_k h[n][k] * W[k][o]   (self-loop GEMM)
// ---------------------------------------------------------------------------
__global__ __launch_bounds__(256) void gemm_selfloop(
    const float* __restrict__ h, const float* __restrict__ W,
    const float* __restrict__ bias, float* __restrict__ out, int n_nodes)
{
    const int tid = threadIdx.x;
    const int ty = tid >> 4, tx = tid & 15;
    const int node0 = blockIdx.x * 128 + ty * 8;
    const int o0 = tx * 8;

    float acc[8][8];
#pragma unroll
    for (int j = 0; j < 8; ++j)
#pragma unroll
        for (int i = 0; i < 8; ++i) acc[j][i] = 0.f;

    int nidx[8];
#pragma unroll
    for (int j = 0; j < 8; ++j) {
        int n = node0 + j;
        nidx[j] = n < n_nodes ? n : (n_nodes - 1);
    }

    for (int k = 0; k < IN_F; k += 4) {
        float hsv[8][4];
#pragma unroll
        for (int j = 0; j < 8; ++j) {
            float4 hv = *reinterpret_cast<const float4*>(h + (size_t)nidx[j] * IN_F + k);
            *reinterpret_cast<float4*>(hsv[j]) = hv;
        }
#pragma unroll
        for (int kk = 0; kk < 4; ++kk) {
            const float* wrow = W + (size_t)(k + kk) * OUT_F + o0;
            float wr[8];
            *reinterpret_cast<float4*>(wr)     = *reinterpret_cast<const float4*>(wrow);
            *reinterpret_cast<float4*>(wr + 4) = *reinterpret_cast<const float4*>(wrow + 4);
#pragma unroll
            for (int j = 0; j < 8; ++j) {
                const float hk = hsv[j][kk];
#pragma unroll
                for (int i = 0; i < 8; ++i)
                    acc[j][i] = fmaf(hk, wr[i], acc[j][i]);
            }
        }
    }

    float br[8];
    *reinterpret_cast<float4*>(br)     = *reinterpret_cast<const float4*>(bias + o0);
    *reinterpret_cast<float4*>(br + 4) = *reinterpret_cast<const float4*>(bias + o0 + 4);

#pragma unroll
    for (int j = 0; j < 8; ++j) {
        int n = node0 + j;
        if (n < n_nodes) {
            float4 v0, v1;
            v0.x = acc[j][0] + br[0]; v0.y = acc[j][1] + br[1];
            v0.z = acc[j][2] + br[2]; v0.w = acc[j][3] + br[3];
            v1.x = acc[j][4] + br[4]; v1.y = acc[j][5] + br[5];
            v1.z = acc[j][6] + br[6]; v1.w = acc[j][7] + br[7];
            float* op = out + (size_t)n * OUT_F + o0;
            *reinterpret_cast<float4*>(op)     = v0;
            *reinterpret_cast<float4*>(op + 4) = v1;
        }
    }
}

// ---------------------------------------------------------------------------
// CSR build: histogram -> scan -> fill (packed int2 meta {src|rel<<20, norm}).
// ---------------------------------------------------------------------------
__global__ __launch_bounds__(256) void hist_dst(
    const int* __restrict__ dst, int* __restrict__ cnt, int n_edges)
{
    int e = blockIdx.x * 256 + threadIdx.x;
    if (e < n_edges) atomicAdd(&cnt[dst[e]], 1);
}

__global__ __launch_bounds__(256) void block_sums(
    const int* __restrict__ cnt, int* __restrict__ part, int n)
{
    __shared__ int sdata[256];
    int i = blockIdx.x * 256 + threadIdx.x;
    sdata[threadIdx.x] = (i < n) ? cnt[i] : 0;
    __syncthreads();
    for (int s = 128; s > 0; s >>= 1) {
        if (threadIdx.x < s) sdata[threadIdx.x] += sdata[threadIdx.x + s];
        __syncthreads();
    }
    if (threadIdx.x == 0) part[blockIdx.x] = sdata[0];
}

__global__ __launch_bounds__(512) void scan_partials(int* __restrict__ part, int nb)
{
    __shared__ int buf[512];
    int tid = threadIdx.x;
    int v = (tid < nb) ? part[tid] : 0;
    buf[tid] = v;
    __syncthreads();
    for (int ofs = 1; ofs < 512; ofs <<= 1) {
        int t = (tid >= ofs) ? buf[tid - ofs] : 0;
        __syncthreads();
        buf[tid] += t;
        __syncthreads();
    }
    if (tid < nb) part[tid] = buf[tid] - v;   // exclusive
}

__global__ __launch_bounds__(256) void write_off(
    const int* __restrict__ cnt, const int* __restrict__ part,
    int* __restrict__ off, int* __restrict__ cur, int n, int n_edges)
{
    __shared__ int buf[256];
    int tid = threadIdx.x;
    int i = blockIdx.x * 256 + tid;
    int v = (i < n) ? cnt[i] : 0;
    buf[tid] = v;
    __syncthreads();
    for (int ofs = 1; ofs < 256; ofs <<= 1) {
        int t = (tid >= ofs) ? buf[tid - ofs] : 0;
        __syncthreads();
        buf[tid] += t;
        __syncthreads();
    }
    int excl = buf[tid] - v + part[blockIdx.x];
    if (i < n) { off[i] = excl; cur[i] = excl; }
    if (i == n - 1) off[n] = n_edges;
}

__global__ __launch_bounds__(256) void fill_csr2(
    const int* __restrict__ src, const int* __restrict__ dst,
    const int* __restrict__ rel, const float* __restrict__ norm,
    int* __restrict__ cur, int2* __restrict__ emeta, int n_edges)
{
    int e = blockIdx.x * 256 + threadIdx.x;
    if (e < n_edges) {
        int d = dst[e];
        int p = atomicAdd(&cur[d], 1);
        int2 m;
        m.x = src[e] | (rel[e] << 20);
        m.y = __float_as_int(norm[e]);
        emeta[p] = m;
    }
}

// ---------------------------------------------------------------------------
// Prep: weight f32 -> fp16x2-packed, i-pair-per-output layout, XOR-swizzled.
// Tile word wp = b*32 + pos*4 + ip, where pos = o ^ (b&7), content =
// {w[b][2ip][o], w[b][2ip+1][o]} as half2 (RNE via _Float16 cast).
// ---------------------------------------------------------------------------
__global__ __launch_bounds__(256) void prep_w16(
    const float* __restrict__ weight, uint32_t* __restrict__ wsw)
{
    int t = blockIdx.x * 256 + threadIdx.x;          // 0 .. 64*512-1
    if (t >= NUM_RELS * 512) return;
    int r   = t >> 9;
    int wp  = t & 511;
    int b   = wp >> 5;
    int pos = (wp >> 2) & 7;
    int ip  = wp & 3;
    int o   = pos ^ (b & 7);
    const float* s = weight + (size_t)r * 1024 + b * 64 + (2 * ip) * 8 + o;
    half2v v;
    v.x = (_Float16)s[0];
    v.y = (_Float16)s[8];
    wsw[t] = __builtin_bit_cast(uint32_t, v);
}

// ---------------------------------------------------------------------------
// Hot kernel v4: grid-stride over dst nodes, one wave per node.
// Per edge: stage 2KB fp16 w-tile (2 coalesced uint4 loads -> 2 linear
// ds_write_b128), read back 2 swizzled ds_read_b128 (bandwidth-minimal
// 8-lane/group), h converted f32->fp16 via cvt_pkrtz, 8 v_dot2_f32_f16.
// 1-deep prefetch, no clamps (emeta padded with a zeroed entry at E).
// lane: b = lane>>2 (BDD block), outputs b*8 + 2q + {0,1}, q = lane&3.
// ---------------------------------------------------------------------------
__global__ __launch_bounds__(256) void gather_nodes4(
    const float* __restrict__ h, const uint32_t* __restrict__ wsw,
    const int* __restrict__ off, const int2* __restrict__ emeta,
    float* __restrict__ out, int n_nodes)
{
    __shared__ uint32_t lds[4][512];

    const int lane = threadIdx.x & 63;
    const int wid  = threadIdx.x >> 6;
    const int b = lane >> 2;
    const int q = lane & 3;

    uint4* slot4 = reinterpret_cast<uint4*>(lds[wid]);
    const uint4* wsw4 = reinterpret_cast<const uint4*>(wsw);

    const int idx0 = b * 8 + ((2 * q)     ^ (b & 7));
    const int idx1 = b * 8 + ((2 * q + 1) ^ (b & 7));

    for (int d = blockIdx.x * 4 + wid; d < n_nodes; d += gridDim.x * 4) {
        const int beg = off[d];
        const int end = off[d + 1];
        float a0 = 0.f, a1 = 0.f;

        if (beg < end) {
            int2 me = emeta[beg];
            uint32_t sr = (uint32_t)me.x;
            const uint4* wp = wsw4 + (sr >> 20) * 128;
            uint4 wa = wp[lane], wb = wp[64 + lane];
            const float4* hr = reinterpret_cast<const float4*>(
                h + (size_t)(sr & 0xFFFFFu) * IN_F + b * 8);
            float4 hA = hr[0], hB = hr[1];

            for (int j = beg; j < end; ++j) {
                // prefetch next edge (emeta padded: j+1 <= E always valid)
                int2 mn = emeta[j + 1];
                uint32_t srn = (uint32_t)mn.x;
                const uint4* wpn = wsw4 + (srn >> 20) * 128;
                uint4 wna = wpn[lane], wnb = wpn[64 + lane];
                const float4* hrn = reinterpret_cast<const float4*>(
                    h + (size_t)(srn & 0xFFFFFu) * IN_F + b * 8);
                float4 hnA = hrn[0], hnB = hrn[1];

                // stage current w tile (linear b128 writes, conflict-free)
                slot4[lane]      = wa;
                slot4[64 + lane] = wb;

                uint32_t h01 = __builtin_bit_cast(uint32_t, __builtin_amdgcn_cvt_pkrtz(hA.x, hA.y));
                uint32_t h23 = __builtin_bit_cast(uint32_t, __builtin_amdgcn_cvt_pkrtz(hA.z, hA.w));
                uint32_t h45 = __builtin_bit_cast(uint32_t, __builtin_amdgcn_cvt_pkrtz(hB.x, hB.y));
                uint32_t h67 = __builtin_bit_cast(uint32_t, __builtin_amdgcn_cvt_pkrtz(hB.z, hB.w));

                uint4 r0 = slot4[idx0];
                uint4 r1 = slot4[idx1];

                float m0 = dot2f(h01, r0.x, 0.f);
                m0 = dot2f(h23, r0.y, m0);
                m0 = dot2f(h45, r0.z, m0);
                m0 = dot2f(h67, r0.w, m0);
                float m1 = dot2f(h01, r1.x, 0.f);
                m1 = dot2f(h23, r1.y, m1);
                m1 = dot2f(h45, r1.z, m1);
                m1 = dot2f(h67, r1.w, m1);

                const float nm = __int_as_float(me.y);
                a0 = fmaf(m0, nm, a0);
                a1 = fmaf(m1, nm, a1);

                me = mn; wa = wna; wb = wnb; hA = hnA; hB = hnB;
            }
        }

        // fused  out = relu(selfloop + agg)
        float2* op = reinterpret_cast<float2*>(out + (size_t)d * OUT_F + b * 8 + 2 * q);
        float2 base = *op;
        float2 res;
        res.x = fmaxf(base.x + a0, 0.f);
        res.y = fmaxf(base.y + a1, 0.f);
        *op = res;
    }
}

extern "C" void kernel_launch(void* const* d_in, const int* in_sizes, int n_in,
                              void* d_out, int out_size, void* d_ws, size_t ws_size,
                              hipStream_t stream)
{
    const float* h      = (const float*)d_in[0];
    const float* norm   = (const float*)d_in[1];
    const float* weight = (const float*)d_in[2];
    const float* loop_w = (const float*)d_in[3];
    const float* bias   = (const float*)d_in[4];
    const int*   src    = (const int*)d_in[5];
    const int*   dst    = (const int*)d_in[6];
    const int*   rel    = (const int*)d_in[7];
    float* out = (float*)d_out;

    // ws layout: cnt[N], off[N+1], cur[N], part[512], wsw[64*512 u32],
    // emeta[E+1] int2  -> ~9.5 MB
    char* wsb = (char*)d_ws;
    int*  cnt   = (int*)wsb;  wsb += sizeof(int) * N_NODES;
    int*  off   = (int*)wsb;  wsb += sizeof(int) * (N_NODES + 1);
    int*  cur   = (int*)wsb;  wsb += sizeof(int) * N_NODES;
    int*  part  = (int*)wsb;  wsb += sizeof(int) * 512;
    wsb = (char*)(((uintptr_t)wsb + 15) & ~(uintptr_t)15);
    uint32_t* wsw = (uint32_t*)wsb; wsb += sizeof(uint32_t) * NUM_RELS * 512;
    int2* emeta = (int2*)wsb; wsb += sizeof(int2) * (N_EDGES + 1);

    hipMemsetAsync(cnt, 0, sizeof(int) * N_NODES, stream);
    hipMemsetAsync(emeta + N_EDGES, 0, sizeof(int2), stream);   // pad entry

    const int egrid = (N_EDGES + 255) / 256;
    hist_dst<<<egrid, 256, 0, stream>>>(dst, cnt, N_EDGES);
    block_sums<<<NB_SCAN, 256, 0, stream>>>(cnt, part, N_NODES);
    scan_partials<<<1, 512, 0, stream>>>(part, NB_SCAN);
    write_off<<<NB_SCAN, 256, 0, stream>>>(cnt, part, off, cur, N_NODES, N_EDGES);
    fill_csr2<<<egrid, 256, 0, stream>>>(src, dst, rel, norm, cur, emeta, N_EDGES);
    prep_w16<<<(NUM_RELS * 512 + 255) / 256, 256, 0, stream>>>(weight, wsw);

    gemm_selfloop<<<(N_NODES + 127) / 128, 256, 0, stream>>>(h, loop_w, bias, out, N_NODES);
    gather_nodes4<<<2048, 256, 0, stream>>>(h, wsw, off, emeta, out, N_NODES);
}

// Round 6
// 351.161 us; speedup vs baseline: 1.1238x; 1.1238x over previous
//
#include <hip/hip_runtime.h>
#include <stdint.h>

#define N_NODES 100000
#define N_EDGES 1000000
#define IN_F 128
#define OUT_F 128
#define NUM_RELS 64
#define NB_SCAN ((N_NODES + 255) / 256)   // 391 blocks for the scan

typedef _Float16 half2v __attribute__((ext_vector_type(2)));

__device__ __forceinline__ float dot2f(uint32_t hu, uint32_t wu, float acc) {
#if __has_builtin(__builtin_amdgcn_fdot2)
    return __builtin_amdgcn_fdot2(__builtin_bit_cast(half2v, hu),
                                  __builtin_bit_cast(half2v, wu), acc, false);
#else
    half2v a = __builtin_bit_cast(half2v, hu);
    half2v b = __builtin_bit_cast(half2v, wu);
    acc = fmaf((float)a.x, (float)b.x, acc);
    acc = fmaf((float)a.y, (float)b.y, acc);
    return acc;
#endif
}

// ---------------------------------------------------------------------------
// Kernel A: out[n][o] = bias[o] + sum_k h[n][k] * W[k][o]   (self-loop GEMM)
// ---------------------------------------------------------------------------
__global__ __launch_bounds__(256) void gemm_selfloop(
    const float* __restrict__ h, const float* __restrict__ W,
    const float* __restrict__ bias, float* __restrict__ out, int n_nodes)
{
    const int tid = threadIdx.x;
    const int ty = tid >> 4, tx = tid & 15;
    const int node0 = blockIdx.x * 128 + ty * 8;
    const int o0 = tx * 8;

    float acc[8][8];
#pragma unroll
    for (int j = 0; j < 8; ++j)
#pragma unroll
        for (int i = 0; i < 8; ++i) acc[j][i] = 0.f;

    int nidx[8];
#pragma unroll
    for (int j = 0; j < 8; ++j) {
        int n = node0 + j;
        nidx[j] = n < n_nodes ? n : (n_nodes - 1);
    }

    for (int k = 0; k < IN_F; k += 4) {
        float hsv[8][4];
#pragma unroll
        for (int j = 0; j < 8; ++j) {
            float4 hv = *reinterpret_cast<const float4*>(h + (size_t)nidx[j] * IN_F + k);
            *reinterpret_cast<float4*>(hsv[j]) = hv;
        }
#pragma unroll
        for (int kk = 0; kk < 4; ++kk) {
            const float* wrow = W + (size_t)(k + kk) * OUT_F + o0;
            float wr[8];
            *reinterpret_cast<float4*>(wr)     = *reinterpret_cast<const float4*>(wrow);
            *reinterpret_cast<float4*>(wr + 4) = *reinterpret_cast<const float4*>(wrow + 4);
#pragma unroll
            for (int j = 0; j < 8; ++j) {
                const float hk = hsv[j][kk];
#pragma unroll
                for (int i = 0; i < 8; ++i)
                    acc[j][i] = fmaf(hk, wr[i], acc[j][i]);
            }
        }
    }

    float br[8];
    *reinterpret_cast<float4*>(br)     = *reinterpret_cast<const float4*>(bias + o0);
    *reinterpret_cast<float4*>(br + 4) = *reinterpret_cast<const float4*>(bias + o0 + 4);

#pragma unroll
    for (int j = 0; j < 8; ++j) {
        int n = node0 + j;
        if (n < n_nodes) {
            float4 v0, v1;
            v0.x = acc[j][0] + br[0]; v0.y = acc[j][1] + br[1];
            v0.z = acc[j][2] + br[2]; v0.w = acc[j][3] + br[3];
            v1.x = acc[j][4] + br[4]; v1.y = acc[j][5] + br[5];
            v1.z = acc[j][6] + br[6]; v1.w = acc[j][7] + br[7];
            float* op = out + (size_t)n * OUT_F + o0;
            *reinterpret_cast<float4*>(op)     = v0;
            *reinterpret_cast<float4*>(op + 4) = v1;
        }
    }
}

// ---------------------------------------------------------------------------
// CSR build: histogram -> scan -> fill (packed int2 meta {src|rel<<20, norm}).
// ---------------------------------------------------------------------------
__global__ __launch_bounds__(256) void hist_dst(
    const int* __restrict__ dst, int* __restrict__ cnt, int n_edges)
{
    int e = blockIdx.x * 256 + threadIdx.x;
    if (e < n_edges) atomicAdd(&cnt[dst[e]], 1);
}

__global__ __launch_bounds__(256) void block_sums(
    const int* __restrict__ cnt, int* __restrict__ part, int n)
{
    __shared__ int sdata[256];
    int i = blockIdx.x * 256 + threadIdx.x;
    sdata[threadIdx.x] = (i < n) ? cnt[i] : 0;
    __syncthreads();
    for (int s = 128; s > 0; s >>= 1) {
        if (threadIdx.x < s) sdata[threadIdx.x] += sdata[threadIdx.x + s];
        __syncthreads();
    }
    if (threadIdx.x == 0) part[blockIdx.x] = sdata[0];
}

__global__ __launch_bounds__(512) void scan_partials(int* __restrict__ part, int nb)
{
    __shared__ int buf[512];
    int tid = threadIdx.x;
    int v = (tid < nb) ? part[tid] : 0;
    buf[tid] = v;
    __syncthreads();
    for (int ofs = 1; ofs < 512; ofs <<= 1) {
        int t = (tid >= ofs) ? buf[tid - ofs] : 0;
        __syncthreads();
        buf[tid] += t;
        __syncthreads();
    }
    if (tid < nb) part[tid] = buf[tid] - v;   // exclusive
}

__global__ __launch_bounds__(256) void write_off(
    const int* __restrict__ cnt, const int* __restrict__ part,
    int* __restrict__ off, int* __restrict__ cur, int n, int n_edges)
{
    __shared__ int buf[256];
    int tid = threadIdx.x;
    int i = blockIdx.x * 256 + tid;
    int v = (i < n) ? cnt[i] : 0;
    buf[tid] = v;
    __syncthreads();
    for (int ofs = 1; ofs < 256; ofs <<= 1) {
        int t = (tid >= ofs) ? buf[tid - ofs] : 0;
        __syncthreads();
        buf[tid] += t;
        __syncthreads();
    }
    int excl = buf[tid] - v + part[blockIdx.x];
    if (i < n) { off[i] = excl; cur[i] = excl; }
    if (i == n - 1) off[n] = n_edges;
}

__global__ __launch_bounds__(256) void fill_csr2(
    const int* __restrict__ src, const int* __restrict__ dst,
    const int* __restrict__ rel, const float* __restrict__ norm,
    int* __restrict__ cur, int2* __restrict__ emeta, int n_edges)
{
    int e = blockIdx.x * 256 + threadIdx.x;
    if (e < n_edges) {
        int d = dst[e];
        int p = atomicAdd(&cur[d], 1);
        int2 m;
        m.x = src[e] | (rel[e] << 20);
        m.y = __float_as_int(norm[e]);
        emeta[p] = m;
    }
}

// ---------------------------------------------------------------------------
// Prep: weight f32 -> fp16x2 packed for the LDS-resident table.
// Word index within rel tile: k*64 + l  (k = 0..7, l = lane 0..63)
//   lane l owns BDD block b = l>>2, output pair q = l&3
//   k encodes (ip = k>>1, oc = k&1): o = 2q + oc, inputs (2ip, 2ip+1)
//   content = half2{ w[r][b][2ip][o], w[r][b][2ip+1][o] }
// Gather reads word r*512 + k*64 + lane -> banks = lane%32, conflict-free.
// ---------------------------------------------------------------------------
__global__ __launch_bounds__(256) void prep_w16(
    const float* __restrict__ weight, uint32_t* __restrict__ wsw)
{
    int t = blockIdx.x * 256 + threadIdx.x;          // 0 .. 64*512-1
    if (t >= NUM_RELS * 512) return;
    int r  = t >> 9;
    int w9 = t & 511;
    int k  = w9 >> 6;
    int l  = w9 & 63;
    int b  = l >> 2;
    int q  = l & 3;
    int ip = k >> 1;
    int oc = k & 1;
    int o  = 2 * q + oc;
    const float* s = weight + (size_t)r * 1024 + b * 64 + (2 * ip) * 8 + o;
    half2v v;
    v.x = (_Float16)s[0];
    v.y = (_Float16)s[8];
    wsw[t] = __builtin_bit_cast(uint32_t, v);
}

// ---------------------------------------------------------------------------
// Hot kernel v5: entire fp16 weight table (128 KB) resident in LDS.
// 1024-thread workgroups (16 waves, 1 block/CU), grid-stride one wave per
// dst node. Per edge: 1 meta load + 2 h float4 loads (global) +
// 8 ds_read_b32 (immediate offsets, conflict-free) + 4 cvt_pkrtz + 8 fdot2.
// 2-deep meta prefetch, 1-deep h prefetch; emeta padded with 2 zero entries.
// ---------------------------------------------------------------------------
__global__ __launch_bounds__(1024, 1) void gather_nodes5(
    const float* __restrict__ h, const uint32_t* __restrict__ wsw,
    const int* __restrict__ off, const int2* __restrict__ emeta,
    float* __restrict__ out, int n_nodes)
{
    __shared__ uint32_t wlds[NUM_RELS * 512];   // 128 KB

    // cooperative stage of the whole table: 1024 threads x 8 uint4
    {
        uint4* l4 = reinterpret_cast<uint4*>(wlds);
        const uint4* g4 = reinterpret_cast<const uint4*>(wsw);
        int t = threadIdx.x;
#pragma unroll
        for (int k = 0; k < 8; ++k)
            l4[t + k * 1024] = g4[t + k * 1024];
    }
    __syncthreads();

    const int lane = threadIdx.x & 63;
    const int wid  = threadIdx.x >> 6;          // 0..15
    const int b = lane >> 2;
    const int q = lane & 3;

    for (int d = blockIdx.x * 16 + wid; d < n_nodes; d += gridDim.x * 16) {
        const int beg = off[d];
        const int end = off[d + 1];
        float a0 = 0.f, a1 = 0.f;

        if (beg < end) {
            int2 me = emeta[beg];
            int2 mn = emeta[beg + 1];           // pad guarantees validity
            const float4* hr = reinterpret_cast<const float4*>(
                h + (size_t)((uint32_t)me.x & 0xFFFFFu) * IN_F + b * 8);
            float4 hA = hr[0], hB = hr[1];

            for (int j = beg; j < end; ++j) {
                int2 mq = emeta[j + 2];         // 2-deep meta prefetch
                const float4* hrn = reinterpret_cast<const float4*>(
                    h + (size_t)((uint32_t)mn.x & 0xFFFFFu) * IN_F + b * 8);
                float4 hnA = hrn[0], hnB = hrn[1];   // 1-deep h prefetch

                const uint32_t base = ((uint32_t)me.x >> 20) * 512 + lane;
                uint32_t w0 = wlds[base];
                uint32_t w1 = wlds[base + 64];
                uint32_t w2 = wlds[base + 128];
                uint32_t w3 = wlds[base + 192];
                uint32_t w4 = wlds[base + 256];
                uint32_t w5 = wlds[base + 320];
                uint32_t w6 = wlds[base + 384];
                uint32_t w7 = wlds[base + 448];

                uint32_t h01 = __builtin_bit_cast(uint32_t, __builtin_amdgcn_cvt_pkrtz(hA.x, hA.y));
                uint32_t h23 = __builtin_bit_cast(uint32_t, __builtin_amdgcn_cvt_pkrtz(hA.z, hA.w));
                uint32_t h45 = __builtin_bit_cast(uint32_t, __builtin_amdgcn_cvt_pkrtz(hB.x, hB.y));
                uint32_t h67 = __builtin_bit_cast(uint32_t, __builtin_amdgcn_cvt_pkrtz(hB.z, hB.w));

                float m0 = dot2f(h01, w0, 0.f);
                m0 = dot2f(h23, w2, m0);
                m0 = dot2f(h45, w4, m0);
                m0 = dot2f(h67, w6, m0);
                float m1 = dot2f(h01, w1, 0.f);
                m1 = dot2f(h23, w3, m1);
                m1 = dot2f(h45, w5, m1);
                m1 = dot2f(h67, w7, m1);

                const float nm = __int_as_float(me.y);
                a0 = fmaf(m0, nm, a0);
                a1 = fmaf(m1, nm, a1);

                me = mn; mn = mq; hA = hnA; hB = hnB;
            }
        }

        // fused  out = relu(selfloop + agg)
        float2* op = reinterpret_cast<float2*>(out + (size_t)d * OUT_F + b * 8 + 2 * q);
        float2 base2 = *op;
        float2 res;
        res.x = fmaxf(base2.x + a0, 0.f);
        res.y = fmaxf(base2.y + a1, 0.f);
        *op = res;
    }
}

extern "C" void kernel_launch(void* const* d_in, const int* in_sizes, int n_in,
                              void* d_out, int out_size, void* d_ws, size_t ws_size,
                              hipStream_t stream)
{
    const float* h      = (const float*)d_in[0];
    const float* norm   = (const float*)d_in[1];
    const float* weight = (const float*)d_in[2];
    const float* loop_w = (const float*)d_in[3];
    const float* bias   = (const float*)d_in[4];
    const int*   src    = (const int*)d_in[5];
    const int*   dst    = (const int*)d_in[6];
    const int*   rel    = (const int*)d_in[7];
    float* out = (float*)d_out;

    // ws layout: cnt[N], off[N+1], cur[N], part[512], wsw[64*512 u32],
    // emeta[E+2] int2  -> ~9.5 MB
    char* wsb = (char*)d_ws;
    int*  cnt   = (int*)wsb;  wsb += sizeof(int) * N_NODES;
    int*  off   = (int*)wsb;  wsb += sizeof(int) * (N_NODES + 1);
    int*  cur   = (int*)wsb;  wsb += sizeof(int) * N_NODES;
    int*  part  = (int*)wsb;  wsb += sizeof(int) * 512;
    wsb = (char*)(((uintptr_t)wsb + 15) & ~(uintptr_t)15);
    uint32_t* wsw = (uint32_t*)wsb; wsb += sizeof(uint32_t) * NUM_RELS * 512;
    int2* emeta = (int2*)wsb; wsb += sizeof(int2) * (N_EDGES + 2);

    hipMemsetAsync(cnt, 0, sizeof(int) * N_NODES, stream);
    hipMemsetAsync(emeta + N_EDGES, 0, 2 * sizeof(int2), stream);   // pad entries

    const int egrid = (N_EDGES + 255) / 256;
    hist_dst<<<egrid, 256, 0, stream>>>(dst, cnt, N_EDGES);
    block_sums<<<NB_SCAN, 256, 0, stream>>>(cnt, part, N_NODES);
    scan_partials<<<1, 512, 0, stream>>>(part, NB_SCAN);
    write_off<<<NB_SCAN, 256, 0, stream>>>(cnt, part, off, cur, N_NODES, N_EDGES);
    fill_csr2<<<egrid, 256, 0, stream>>>(src, dst, rel, norm, cur, emeta, N_EDGES);
    prep_w16<<<(NUM_RELS * 512 + 255) / 256, 256, 0, stream>>>(weight, wsw);

    gemm_selfloop<<<(N_NODES + 127) / 128, 256, 0, stream>>>(h, loop_w, bias, out, N_NODES);
    gather_nodes5<<<1024, 1024, 0, stream>>>(h, wsw, off, emeta, out, N_NODES);
}

// Round 7
// 333.669 us; speedup vs baseline: 1.1827x; 1.0524x over previous
//
#include <hip/hip_runtime.h>
#include <stdint.h>

#define N_NODES 100000
#define N_EDGES 1000000
#define IN_F 128
#define OUT_F 128
#define NUM_RELS 64
#define NB_SCAN ((N_NODES + 255) / 256)   // 391 blocks for the scan
#define N_WAVES 16384                     // gather waves (1024 blocks x 16)

typedef _Float16 half2v __attribute__((ext_vector_type(2)));

__device__ __forceinline__ float dot2f(uint32_t hu, uint32_t wu, float acc) {
#if __has_builtin(__builtin_amdgcn_fdot2)
    return __builtin_amdgcn_fdot2(__builtin_bit_cast(half2v, hu),
                                  __builtin_bit_cast(half2v, wu), acc, false);
#else
    half2v a = __builtin_bit_cast(half2v, hu);
    half2v b = __builtin_bit_cast(half2v, wu);
    acc = fmaf((float)a.x, (float)b.x, acc);
    acc = fmaf((float)a.y, (float)b.y, acc);
    return acc;
#endif
}

// ---------------------------------------------------------------------------
// Kernel A: out[n][o] = bias[o] + sum_k h[n][k] * W[k][o]   (self-loop GEMM)
// ---------------------------------------------------------------------------
__global__ __launch_bounds__(256) void gemm_selfloop(
    const float* __restrict__ h, const float* __restrict__ W,
    const float* __restrict__ bias, float* __restrict__ out, int n_nodes)
{
    const int tid = threadIdx.x;
    const int ty = tid >> 4, tx = tid & 15;
    const int node0 = blockIdx.x * 128 + ty * 8;
    const int o0 = tx * 8;

    float acc[8][8];
#pragma unroll
    for (int j = 0; j < 8; ++j)
#pragma unroll
        for (int i = 0; i < 8; ++i) acc[j][i] = 0.f;

    int nidx[8];
#pragma unroll
    for (int j = 0; j < 8; ++j) {
        int n = node0 + j;
        nidx[j] = n < n_nodes ? n : (n_nodes - 1);
    }

    for (int k = 0; k < IN_F; k += 4) {
        float hsv[8][4];
#pragma unroll
        for (int j = 0; j < 8; ++j) {
            float4 hv = *reinterpret_cast<const float4*>(h + (size_t)nidx[j] * IN_F + k);
            *reinterpret_cast<float4*>(hsv[j]) = hv;
        }
#pragma unroll
        for (int kk = 0; kk < 4; ++kk) {
            const float* wrow = W + (size_t)(k + kk) * OUT_F + o0;
            float wr[8];
            *reinterpret_cast<float4*>(wr)     = *reinterpret_cast<const float4*>(wrow);
            *reinterpret_cast<float4*>(wr + 4) = *reinterpret_cast<const float4*>(wrow + 4);
#pragma unroll
            for (int j = 0; j < 8; ++j) {
                const float hk = hsv[j][kk];
#pragma unroll
                for (int i = 0; i < 8; ++i)
                    acc[j][i] = fmaf(hk, wr[i], acc[j][i]);
            }
        }
    }

    float br[8];
    *reinterpret_cast<float4*>(br)     = *reinterpret_cast<const float4*>(bias + o0);
    *reinterpret_cast<float4*>(br + 4) = *reinterpret_cast<const float4*>(bias + o0 + 4);

#pragma unroll
    for (int j = 0; j < 8; ++j) {
        int n = node0 + j;
        if (n < n_nodes) {
            float4 v0, v1;
            v0.x = acc[j][0] + br[0]; v0.y = acc[j][1] + br[1];
            v0.z = acc[j][2] + br[2]; v0.w = acc[j][3] + br[3];
            v1.x = acc[j][4] + br[4]; v1.y = acc[j][5] + br[5];
            v1.z = acc[j][6] + br[6]; v1.w = acc[j][7] + br[7];
            float* op = out + (size_t)n * OUT_F + o0;
            *reinterpret_cast<float4*>(op)     = v0;
            *reinterpret_cast<float4*>(op + 4) = v1;
        }
    }
}

// ---------------------------------------------------------------------------
// prep (weight f32 -> fp16x2 table, same layout as R6) + dst histogram,
// fused into one launch (disjoint thread ranges).
// Table word within rel tile: k*64 + l; lane l owns b=l>>2, q=l&3;
// k = ip*2+oc -> o = 2q+oc, inputs (2ip, 2ip+1).
// ---------------------------------------------------------------------------
__global__ __launch_bounds__(256) void prep_and_hist(
    const float* __restrict__ weight, uint32_t* __restrict__ wsw,
    const int* __restrict__ dst, int* __restrict__ cnt, int n_edges)
{
    int t = blockIdx.x * 256 + threadIdx.x;
    if (t < NUM_RELS * 512) {
        int r  = t >> 9;
        int w9 = t & 511;
        int k  = w9 >> 6;
        int l  = w9 & 63;
        int b  = l >> 2;
        int q  = l & 3;
        int ip = k >> 1;
        int oc = k & 1;
        int o  = 2 * q + oc;
        const float* s = weight + (size_t)r * 1024 + b * 64 + (2 * ip) * 8 + o;
        half2v v;
        v.x = (_Float16)s[0];
        v.y = (_Float16)s[8];
        wsw[t] = __builtin_bit_cast(uint32_t, v);
    }
    int e = t - NUM_RELS * 512;
    if (e >= 0 && e < n_edges) atomicAdd(&cnt[dst[e]], 1);
}

__global__ __launch_bounds__(256) void block_sums(
    const int* __restrict__ cnt, int* __restrict__ part, int n)
{
    __shared__ int sdata[256];
    int i = blockIdx.x * 256 + threadIdx.x;
    sdata[threadIdx.x] = (i < n) ? cnt[i] : 0;
    __syncthreads();
    for (int s = 128; s > 0; s >>= 1) {
        if (threadIdx.x < s) sdata[threadIdx.x] += sdata[threadIdx.x + s];
        __syncthreads();
    }
    if (threadIdx.x == 0) part[blockIdx.x] = sdata[0];
}

__global__ __launch_bounds__(512) void scan_partials(int* __restrict__ part, int nb)
{
    __shared__ int buf[512];
    int tid = threadIdx.x;
    int v = (tid < nb) ? part[tid] : 0;
    buf[tid] = v;
    __syncthreads();
    for (int ofs = 1; ofs < 512; ofs <<= 1) {
        int t = (tid >= ofs) ? buf[tid - ofs] : 0;
        __syncthreads();
        buf[tid] += t;
        __syncthreads();
    }
    if (tid < nb) part[tid] = buf[tid] - v;   // exclusive
}

__global__ __launch_bounds__(256) void write_off(
    const int* __restrict__ cnt, const int* __restrict__ part,
    int* __restrict__ off, int* __restrict__ cur, int n, int n_edges)
{
    __shared__ int buf[256];
    int tid = threadIdx.x;
    int i = blockIdx.x * 256 + tid;
    int v = (i < n) ? cnt[i] : 0;
    buf[tid] = v;
    __syncthreads();
    for (int ofs = 1; ofs < 256; ofs <<= 1) {
        int t = (tid >= ofs) ? buf[tid - ofs] : 0;
        __syncthreads();
        buf[tid] += t;
        __syncthreads();
    }
    int excl = buf[tid] - v + part[blockIdx.x];
    if (i < n) { off[i] = excl; cur[i] = excl; }
    if (i == n - 1) off[n] = n_edges;
}

// ---------------------------------------------------------------------------
// fill CSR (packed int2 meta {src|rel<<20, norm}) + balanced wave partition.
// wstart[w] = first node of wave w's contiguous node range; wave w owns
// nodes [wstart[w], wstart[w+1]) and therefore the contiguous edge slice
// [off[wstart[w]], off[wstart[w+1]]).
// ---------------------------------------------------------------------------
__global__ __launch_bounds__(256) void fill_and_part(
    const int* __restrict__ src, const int* __restrict__ dst,
    const int* __restrict__ rel, const float* __restrict__ norm,
    int* __restrict__ cur, int2* __restrict__ emeta,
    const int* __restrict__ off, int* __restrict__ wstart, int n_edges)
{
    int t = blockIdx.x * 256 + threadIdx.x;
    if (t < n_edges) {
        int d = dst[t];
        int p = atomicAdd(&cur[d], 1);
        int2 m;
        m.x = src[t] | (rel[t] << 20);
        m.y = __float_as_int(norm[t]);
        emeta[p] = m;
    } else {
        int w = t - n_edges;
        if (w <= N_WAVES) {
            if (w == 0) {
                wstart[0] = 0;
            } else if (w == N_WAVES) {
                wstart[N_WAVES] = N_NODES;
            } else {
                int target = (int)(((long long)N_EDGES * w) / N_WAVES);
                // smallest n with off[n+1] > target
                int lo = 0, hi = N_NODES - 1;
                while (lo < hi) {
                    int mid = (lo + hi) >> 1;
                    if (off[mid + 1] > target) hi = mid; else lo = mid + 1;
                }
                wstart[w] = lo;
            }
        }
    }
}

// ---------------------------------------------------------------------------
// Hot kernel v6: fp16 weight table (128 KB) in LDS; each wave owns a
// contiguous node range -> contiguous edge slice. Software pipeline over the
// flat edge stream (meta 3-deep, h 2-deep, w-LDS 1-deep) that never breaks
// at node boundaries; per-node flush = float2 RMW of out + fused ReLU.
// lane: b = lane>>2, outputs b*8 + 2q + {0,1}, q = lane&3.
// ---------------------------------------------------------------------------
__global__ __launch_bounds__(1024, 4) void gather_nodes6(
    const float* __restrict__ h, const uint32_t* __restrict__ wsw,
    const int* __restrict__ off, const int2* __restrict__ emeta,
    const int* __restrict__ wstart, float* __restrict__ out)
{
    __shared__ uint32_t wlds[NUM_RELS * 512];   // 128 KB

    {   // cooperative stage of the whole table: 1024 threads x 8 uint4
        uint4* l4 = reinterpret_cast<uint4*>(wlds);
        const uint4* g4 = reinterpret_cast<const uint4*>(wsw);
        int t = threadIdx.x;
#pragma unroll
        for (int k = 0; k < 8; ++k)
            l4[t + k * 1024] = g4[t + k * 1024];
    }
    __syncthreads();

    const int lane = threadIdx.x & 63;
    const int wid  = threadIdx.x >> 6;          // 0..15
    const int wv   = blockIdx.x * 16 + wid;     // wave id
    const int b = lane >> 2;
    const int q = lane & 3;

    const int n0 = wstart[wv];
    const int n1 = wstart[wv + 1];
    if (n0 >= n1) return;

    int j = off[n0];

    // ---- prime the pipeline (emeta padded with 3 zero entries) ----
    int2 m0 = emeta[j];
    int2 m1 = emeta[j + 1];
    int2 m2 = emeta[j + 2];

    const float4* hr0 = reinterpret_cast<const float4*>(
        h + (size_t)((uint32_t)m0.x & 0xFFFFFu) * IN_F + b * 8);
    float4 h0A = hr0[0], h0B = hr0[1];
    const float4* hr1 = reinterpret_cast<const float4*>(
        h + (size_t)((uint32_t)m1.x & 0xFFFFFu) * IN_F + b * 8);
    float4 h1A = hr1[0], h1B = hr1[1];

    uint32_t base = ((uint32_t)m0.x >> 20) * 512 + (uint32_t)lane;
    uint32_t w0 = wlds[base],       w1 = wlds[base + 64];
    uint32_t w2 = wlds[base + 128], w3 = wlds[base + 192];
    uint32_t w4 = wlds[base + 256], w5 = wlds[base + 320];
    uint32_t w6 = wlds[base + 384], w7 = wlds[base + 448];

    for (int d = n0; d < n1; ++d) {
        const int end_d = off[d + 1];
        float a0 = 0.f, a1 = 0.f;

        while (j < end_d) {
            // ---- prefetches (all for future iterations) ----
            int2 m3 = emeta[j + 3];
            const float4* hr2 = reinterpret_cast<const float4*>(
                h + (size_t)((uint32_t)m2.x & 0xFFFFFu) * IN_F + b * 8);
            float4 h2A = hr2[0], h2B = hr2[1];
            uint32_t bn = ((uint32_t)m1.x >> 20) * 512 + (uint32_t)lane;
            uint32_t wn0 = wlds[bn],       wn1 = wlds[bn + 64];
            uint32_t wn2 = wlds[bn + 128], wn3 = wlds[bn + 192];
            uint32_t wn4 = wlds[bn + 256], wn5 = wlds[bn + 320];
            uint32_t wn6 = wlds[bn + 384], wn7 = wlds[bn + 448];

            // ---- compute edge j (m0 / h0 / w0..w7, all loaded >=1 iter ago)
            uint32_t h01 = __builtin_bit_cast(uint32_t, __builtin_amdgcn_cvt_pkrtz(h0A.x, h0A.y));
            uint32_t h23 = __builtin_bit_cast(uint32_t, __builtin_amdgcn_cvt_pkrtz(h0A.z, h0A.w));
            uint32_t h45 = __builtin_bit_cast(uint32_t, __builtin_amdgcn_cvt_pkrtz(h0B.x, h0B.y));
            uint32_t h67 = __builtin_bit_cast(uint32_t, __builtin_amdgcn_cvt_pkrtz(h0B.z, h0B.w));

            float s0 = dot2f(h01, w0, 0.f);
            s0 = dot2f(h23, w2, s0);
            s0 = dot2f(h45, w4, s0);
            s0 = dot2f(h67, w6, s0);
            float s1 = dot2f(h01, w1, 0.f);
            s1 = dot2f(h23, w3, s1);
            s1 = dot2f(h45, w5, s1);
            s1 = dot2f(h67, w7, s1);

            const float nm = __int_as_float(m0.y);
            a0 = fmaf(s0, nm, a0);
            a1 = fmaf(s1, nm, a1);

            // ---- rotate pipeline ----
            m0 = m1; m1 = m2; m2 = m3;
            h0A = h1A; h0B = h1B; h1A = h2A; h1B = h2B;
            w0 = wn0; w1 = wn1; w2 = wn2; w3 = wn3;
            w4 = wn4; w5 = wn5; w6 = wn6; w7 = wn7;
            ++j;
        }

        // flush: out = relu(selfloop + agg)
        float2* op = reinterpret_cast<float2*>(out + (size_t)d * OUT_F + b * 8 + 2 * q);
        float2 bse = *op;
        float2 res;
        res.x = fmaxf(bse.x + a0, 0.f);
        res.y = fmaxf(bse.y + a1, 0.f);
        *op = res;
    }
}

extern "C" void kernel_launch(void* const* d_in, const int* in_sizes, int n_in,
                              void* d_out, int out_size, void* d_ws, size_t ws_size,
                              hipStream_t stream)
{
    const float* h      = (const float*)d_in[0];
    const float* norm   = (const float*)d_in[1];
    const float* weight = (const float*)d_in[2];
    const float* loop_w = (const float*)d_in[3];
    const float* bias   = (const float*)d_in[4];
    const int*   src    = (const int*)d_in[5];
    const int*   dst    = (const int*)d_in[6];
    const int*   rel    = (const int*)d_in[7];
    float* out = (float*)d_out;

    // ws layout: cnt[N], off[N+1], cur[N], part[512], wstart[N_WAVES+1],
    // wsw[64*512 u32], emeta[E+3] int2  -> ~9.5 MB
    char* wsb = (char*)d_ws;
    int*  cnt    = (int*)wsb;  wsb += sizeof(int) * N_NODES;
    int*  off    = (int*)wsb;  wsb += sizeof(int) * (N_NODES + 1);
    int*  cur    = (int*)wsb;  wsb += sizeof(int) * N_NODES;
    int*  part   = (int*)wsb;  wsb += sizeof(int) * 512;
    int*  wstart = (int*)wsb;  wsb += sizeof(int) * (N_WAVES + 1);
    wsb = (char*)(((uintptr_t)wsb + 15) & ~(uintptr_t)15);
    uint32_t* wsw = (uint32_t*)wsb; wsb += sizeof(uint32_t) * NUM_RELS * 512;
    int2* emeta = (int2*)wsb;  wsb += sizeof(int2) * (N_EDGES + 3);

    hipMemsetAsync(cnt, 0, sizeof(int) * N_NODES, stream);
    hipMemsetAsync(emeta + N_EDGES, 0, 3 * sizeof(int2), stream);   // pads

    const int ph_grid = (NUM_RELS * 512 + N_EDGES + 255) / 256;
    prep_and_hist<<<ph_grid, 256, 0, stream>>>(weight, wsw, dst, cnt, N_EDGES);
    block_sums<<<NB_SCAN, 256, 0, stream>>>(cnt, part, N_NODES);
    scan_partials<<<1, 512, 0, stream>>>(part, NB_SCAN);
    write_off<<<NB_SCAN, 256, 0, stream>>>(cnt, part, off, cur, N_NODES, N_EDGES);
    const int fp_grid = (N_EDGES + N_WAVES + 1 + 255) / 256;
    fill_and_part<<<fp_grid, 256, 0, stream>>>(src, dst, rel, norm, cur, emeta,
                                               off, wstart, N_EDGES);

    gemm_selfloop<<<(N_NODES + 127) / 128, 256, 0, stream>>>(h, loop_w, bias, out, N_NODES);
    gather_nodes6<<<1024, 1024, 0, stream>>>(h, wsw, off, emeta, wstart, out);
}

// Round 11
// 333.478 us; speedup vs baseline: 1.1834x; 1.0006x over previous
//
#include <hip/hip_runtime.h>
#include <stdint.h>

#define N_NODES 100000
#define N_EDGES 1000000
#define IN_F 128
#define OUT_F 128
#define NUM_RELS 64
#define NB_SCAN ((N_NODES + 255) / 256)   // 391 blocks for the scan
#define N_WAVES 16384                     // gather waves (1024 blocks x 16)

typedef _Float16 half2v __attribute__((ext_vector_type(2)));

__device__ __forceinline__ float dot2f(uint32_t hu, uint32_t wu, float acc) {
#if __has_builtin(__builtin_amdgcn_fdot2)
    return __builtin_amdgcn_fdot2(__builtin_bit_cast(half2v, hu),
                                  __builtin_bit_cast(half2v, wu), acc, false);
#else
    half2v a = __builtin_bit_cast(half2v, hu);
    half2v b = __builtin_bit_cast(half2v, wu);
    acc = fmaf((float)a.x, (float)b.x, acc);
    acc = fmaf((float)a.y, (float)b.y, acc);
    return acc;
#endif
}

__device__ __forceinline__ uint32_t pkh2(float x, float y) {
    half2v v;
    v.x = (_Float16)x;    // RNE
    v.y = (_Float16)y;
    return __builtin_bit_cast(uint32_t, v);
}

// ---------------------------------------------------------------------------
// Kernel A: out[n][o] = bias[o] + sum_k h[n][k] * W[k][o]   (self-loop GEMM)
// ---------------------------------------------------------------------------
__global__ __launch_bounds__(256) void gemm_selfloop(
    const float* __restrict__ h, const float* __restrict__ W,
    const float* __restrict__ bias, float* __restrict__ out, int n_nodes)
{
    const int tid = threadIdx.x;
    const int ty = tid >> 4, tx = tid & 15;
    const int node0 = blockIdx.x * 128 + ty * 8;
    const int o0 = tx * 8;

    float acc[8][8];
#pragma unroll
    for (int j = 0; j < 8; ++j)
#pragma unroll
        for (int i = 0; i < 8; ++i) acc[j][i] = 0.f;

    int nidx[8];
#pragma unroll
    for (int j = 0; j < 8; ++j) {
        int n = node0 + j;
        nidx[j] = n < n_nodes ? n : (n_nodes - 1);
    }

    for (int k = 0; k < IN_F; k += 4) {
        float hsv[8][4];
#pragma unroll
        for (int j = 0; j < 8; ++j) {
            float4 hv = *reinterpret_cast<const float4*>(h + (size_t)nidx[j] * IN_F + k);
            *reinterpret_cast<float4*>(hsv[j]) = hv;
        }
#pragma unroll
        for (int kk = 0; kk < 4; ++kk) {
            const float* wrow = W + (size_t)(k + kk) * OUT_F + o0;
            float wr[8];
            *reinterpret_cast<float4*>(wr)     = *reinterpret_cast<const float4*>(wrow);
            *reinterpret_cast<float4*>(wr + 4) = *reinterpret_cast<const float4*>(wrow + 4);
#pragma unroll
            for (int j = 0; j < 8; ++j) {
                const float hk = hsv[j][kk];
#pragma unroll
                for (int i = 0; i < 8; ++i)
                    acc[j][i] = fmaf(hk, wr[i], acc[j][i]);
            }
        }
    }

    float br[8];
    *reinterpret_cast<float4*>(br)     = *reinterpret_cast<const float4*>(bias + o0);
    *reinterpret_cast<float4*>(br + 4) = *reinterpret_cast<const float4*>(bias + o0 + 4);

#pragma unroll
    for (int j = 0; j < 8; ++j) {
        int n = node0 + j;
        if (n < n_nodes) {
            float4 v0, v1;
            v0.x = acc[j][0] + br[0]; v0.y = acc[j][1] + br[1];
            v0.z = acc[j][2] + br[2]; v0.w = acc[j][3] + br[3];
            v1.x = acc[j][4] + br[4]; v1.y = acc[j][5] + br[5];
            v1.z = acc[j][6] + br[6]; v1.w = acc[j][7] + br[7];
            float* op = out + (size_t)n * OUT_F + o0;
            *reinterpret_cast<float4*>(op)     = v0;
            *reinterpret_cast<float4*>(op + 4) = v1;
        }
    }
}

// ---------------------------------------------------------------------------
// prep: weight f32 -> fp16x2 table  +  dst histogram  +  h f32 -> fp16 (RNE),
// fused into one launch (disjoint, block-contiguous thread ranges).
// Table word within rel tile: k*64 + l; lane l owns b=l>>2, q=l&3;
// k = ip*2+oc -> o = 2q+oc, inputs (2ip, 2ip+1).
// ---------------------------------------------------------------------------
__global__ __launch_bounds__(256) void prep_hist_h16(
    const float* __restrict__ weight, uint32_t* __restrict__ wsw,
    const int* __restrict__ dst, int* __restrict__ cnt,
    const float* __restrict__ h, uint4* __restrict__ h16_4,
    int n_edges, int do_h16)
{
    int t = blockIdx.x * 256 + threadIdx.x;
    if (t < NUM_RELS * 512) {
        int r  = t >> 9;
        int w9 = t & 511;
        int k  = w9 >> 6;
        int l  = w9 & 63;
        int b  = l >> 2;
        int q  = l & 3;
        int ip = k >> 1;
        int oc = k & 1;
        int o  = 2 * q + oc;
        const float* s = weight + (size_t)r * 1024 + b * 64 + (2 * ip) * 8 + o;
        half2v v;
        v.x = (_Float16)s[0];
        v.y = (_Float16)s[8];
        wsw[t] = __builtin_bit_cast(uint32_t, v);
        return;
    }
    int e = t - NUM_RELS * 512;
    if (e < n_edges) {
        atomicAdd(&cnt[dst[e]], 1);
        return;
    }
    if (!do_h16) return;
    int t2 = e - n_edges;                       // 0 .. N*IN_F/8-1
    if (t2 < N_NODES * IN_F / 8) {
        const float4* hp = reinterpret_cast<const float4*>(h + (size_t)t2 * 8);
        float4 a = hp[0], c = hp[1];
        uint4 r;
        r.x = pkh2(a.x, a.y);
        r.y = pkh2(a.z, a.w);
        r.z = pkh2(c.x, c.y);
        r.w = pkh2(c.z, c.w);
        h16_4[t2] = r;
    }
}

__global__ __launch_bounds__(256) void block_sums(
    const int* __restrict__ cnt, int* __restrict__ part, int n)
{
    __shared__ int sdata[256];
    int i = blockIdx.x * 256 + threadIdx.x;
    sdata[threadIdx.x] = (i < n) ? cnt[i] : 0;
    __syncthreads();
    for (int s = 128; s > 0; s >>= 1) {
        if (threadIdx.x < s) sdata[threadIdx.x] += sdata[threadIdx.x + s];
        __syncthreads();
    }
    if (threadIdx.x == 0) part[blockIdx.x] = sdata[0];
}

__global__ __launch_bounds__(512) void scan_partials(int* __restrict__ part, int nb)
{
    __shared__ int buf[512];
    int tid = threadIdx.x;
    int v = (tid < nb) ? part[tid] : 0;
    buf[tid] = v;
    __syncthreads();
    for (int ofs = 1; ofs < 512; ofs <<= 1) {
        int t = (tid >= ofs) ? buf[tid - ofs] : 0;
        __syncthreads();
        buf[tid] += t;
        __syncthreads();
    }
    if (tid < nb) part[tid] = buf[tid] - v;   // exclusive
}

__global__ __launch_bounds__(256) void write_off(
    const int* __restrict__ cnt, const int* __restrict__ part,
    int* __restrict__ off, int* __restrict__ cur, int n, int n_edges)
{
    __shared__ int buf[256];
    int tid = threadIdx.x;
    int i = blockIdx.x * 256 + tid;
    int v = (i < n) ? cnt[i] : 0;
    buf[tid] = v;
    __syncthreads();
    for (int ofs = 1; ofs < 256; ofs <<= 1) {
        int t = (tid >= ofs) ? buf[tid - ofs] : 0;
        __syncthreads();
        buf[tid] += t;
        __syncthreads();
    }
    int excl = buf[tid] - v + part[blockIdx.x];
    if (i < n) { off[i] = excl; cur[i] = excl; }
    if (i == n - 1) off[n] = n_edges;
}

// ---------------------------------------------------------------------------
// fill CSR (packed int2 meta {src|rel<<20, norm}) + balanced wave partition.
// ---------------------------------------------------------------------------
__global__ __launch_bounds__(256) void fill_and_part(
    const int* __restrict__ src, const int* __restrict__ dst,
    const int* __restrict__ rel, const float* __restrict__ norm,
    int* __restrict__ cur, int2* __restrict__ emeta,
    const int* __restrict__ off, int* __restrict__ wstart, int n_edges)
{
    int t = blockIdx.x * 256 + threadIdx.x;
    if (t < n_edges) {
        int d = dst[t];
        int p = atomicAdd(&cur[d], 1);
        int2 m;
        m.x = src[t] | (rel[t] << 20);
        m.y = __float_as_int(norm[t]);
        emeta[p] = m;
    } else {
        int w = t - n_edges;
        if (w <= N_WAVES) {
            if (w == 0) {
                wstart[0] = 0;
            } else if (w == N_WAVES) {
                wstart[N_WAVES] = N_NODES;
            } else {
                int target = (int)(((long long)N_EDGES * w) / N_WAVES);
                int lo = 0, hi = N_NODES - 1;
                while (lo < hi) {
                    int mid = (lo + hi) >> 1;
                    if (off[mid + 1] > target) hi = mid; else lo = mid + 1;
                }
                wstart[w] = lo;
            }
        }
    }
}

// ---------------------------------------------------------------------------
// Hot kernel v7: fp16 weight table (128 KB) in LDS; h pre-converted to fp16.
// Per edge: 1 meta load + 1 uint4 h16 load + 8 ds_read_b32 + 8 fdot2 + 2 fma.
// Pipeline: meta 3-deep, h 2-deep, w-LDS 1-deep; off[] prefetched one node
// ahead so node boundaries never stall. Contiguous edge slice per wave.
// ---------------------------------------------------------------------------
__global__ __launch_bounds__(1024, 4) void gather_nodes7(
    const uint4* __restrict__ h16_4, const uint32_t* __restrict__ wsw,
    const int* __restrict__ off, const int2* __restrict__ emeta,
    const int* __restrict__ wstart, float* __restrict__ out)
{
    __shared__ uint32_t wlds[NUM_RELS * 512];   // 128 KB

    {   // cooperative stage of the whole table: 1024 threads x 8 uint4
        uint4* l4 = reinterpret_cast<uint4*>(wlds);
        const uint4* g4 = reinterpret_cast<const uint4*>(wsw);
        int t = threadIdx.x;
#pragma unroll
        for (int k = 0; k < 8; ++k)
            l4[t + k * 1024] = g4[t + k * 1024];
    }
    __syncthreads();

    const int lane = threadIdx.x & 63;
    const int wid  = threadIdx.x >> 6;          // 0..15
    const int wv   = blockIdx.x * 16 + wid;     // wave id
    const int b = lane >> 2;
    const int q = lane & 3;

    const int n0 = wstart[wv];
    const int n1 = wstart[wv + 1];
    if (n0 >= n1) return;

    int j = off[n0];
    int e_next = off[n0 + 1];                   // end of first node

    // ---- prime the pipeline (emeta padded with 3 zero entries) ----
    int2 m0 = emeta[j];
    int2 m1 = emeta[j + 1];
    int2 m2 = emeta[j + 2];
    uint4 hv0 = h16_4[((uint32_t)m0.x & 0xFFFFFu) * 16 + b];
    uint4 hv1 = h16_4[((uint32_t)m1.x & 0xFFFFFu) * 16 + b];

    uint32_t base = ((uint32_t)m0.x >> 20) * 512 + (uint32_t)lane;
    uint32_t w0 = wlds[base],       w1 = wlds[base + 64];
    uint32_t w2 = wlds[base + 128], w3 = wlds[base + 192];
    uint32_t w4 = wlds[base + 256], w5 = wlds[base + 320];
    uint32_t w6 = wlds[base + 384], w7 = wlds[base + 448];

    for (int d = n0; d < n1; ++d) {
        const int idx2 = (d + 2 < n1) ? d + 2 : n1;
        const int e_nn = off[idx2];             // prefetch next node's end
        float a0 = 0.f, a1 = 0.f;

        while (j < e_next) {
            // ---- prefetches (for future iterations) ----
            int2 m3 = emeta[j + 3];
            uint4 hv2 = h16_4[((uint32_t)m2.x & 0xFFFFFu) * 16 + b];
            uint32_t bn = ((uint32_t)m1.x >> 20) * 512 + (uint32_t)lane;
            uint32_t wn0 = wlds[bn],       wn1 = wlds[bn + 64];
            uint32_t wn2 = wlds[bn + 128], wn3 = wlds[bn + 192];
            uint32_t wn4 = wlds[bn + 256], wn5 = wlds[bn + 320];
            uint32_t wn6 = wlds[bn + 384], wn7 = wlds[bn + 448];

            // ---- compute edge j (everything loaded >=1 iteration ago) ----
            float s0 = dot2f(hv0.x, w0, 0.f);
            s0 = dot2f(hv0.y, w2, s0);
            s0 = dot2f(hv0.z, w4, s0);
            s0 = dot2f(hv0.w, w6, s0);
            float s1 = dot2f(hv0.x, w1, 0.f);
            s1 = dot2f(hv0.y, w3, s1);
            s1 = dot2f(hv0.z, w5, s1);
            s1 = dot2f(hv0.w, w7, s1);

            const float nm = __int_as_float(m0.y);
            a0 = fmaf(s0, nm, a0);
            a1 = fmaf(s1, nm, a1);

            // ---- rotate pipeline ----
            m0 = m1; m1 = m2; m2 = m3;
            hv0 = hv1; hv1 = hv2;
            w0 = wn0; w1 = wn1; w2 = wn2; w3 = wn3;
            w4 = wn4; w5 = wn5; w6 = wn6; w7 = wn7;
            ++j;
        }

        // flush: out = relu(selfloop + agg)
        float2* op = reinterpret_cast<float2*>(out + (size_t)d * OUT_F + b * 8 + 2 * q);
        float2 bse = *op;
        float2 res;
        res.x = fmaxf(bse.x + a0, 0.f);
        res.y = fmaxf(bse.y + a1, 0.f);
        *op = res;

        e_next = e_nn;
    }
}

// ---------------------------------------------------------------------------
// Fallback hot kernel (R7 path, h in f32) if ws_size can't hold h16.
// ---------------------------------------------------------------------------
__global__ __launch_bounds__(1024, 4) void gather_nodes6(
    const float* __restrict__ h, const uint32_t* __restrict__ wsw,
    const int* __restrict__ off, const int2* __restrict__ emeta,
    const int* __restrict__ wstart, float* __restrict__ out)
{
    __shared__ uint32_t wlds[NUM_RELS * 512];   // 128 KB
    {
        uint4* l4 = reinterpret_cast<uint4*>(wlds);
        const uint4* g4 = reinterpret_cast<const uint4*>(wsw);
        int t = threadIdx.x;
#pragma unroll
        for (int k = 0; k < 8; ++k)
            l4[t + k * 1024] = g4[t + k * 1024];
    }
    __syncthreads();

    const int lane = threadIdx.x & 63;
    const int wid  = threadIdx.x >> 6;
    const int wv   = blockIdx.x * 16 + wid;
    const int b = lane >> 2;
    const int q = lane & 3;

    const int n0 = wstart[wv];
    const int n1 = wstart[wv + 1];
    if (n0 >= n1) return;

    int j = off[n0];
    int2 m0 = emeta[j];
    int2 m1 = emeta[j + 1];
    int2 m2 = emeta[j + 2];

    const float4* hr0 = reinterpret_cast<const float4*>(
        h + (size_t)((uint32_t)m0.x & 0xFFFFFu) * IN_F + b * 8);
    float4 h0A = hr0[0], h0B = hr0[1];
    const float4* hr1 = reinterpret_cast<const float4*>(
        h + (size_t)((uint32_t)m1.x & 0xFFFFFu) * IN_F + b * 8);
    float4 h1A = hr1[0], h1B = hr1[1];

    uint32_t base = ((uint32_t)m0.x >> 20) * 512 + (uint32_t)lane;
    uint32_t w0 = wlds[base],       w1 = wlds[base + 64];
    uint32_t w2 = wlds[base + 128], w3 = wlds[base + 192];
    uint32_t w4 = wlds[base + 256], w5 = wlds[base + 320];
    uint32_t w6 = wlds[base + 384], w7 = wlds[base + 448];

    for (int d = n0; d < n1; ++d) {
        const int end_d = off[d + 1];
        float a0 = 0.f, a1 = 0.f;

        while (j < end_d) {
            int2 m3 = emeta[j + 3];
            const float4* hr2 = reinterpret_cast<const float4*>(
                h + (size_t)((uint32_t)m2.x & 0xFFFFFu) * IN_F + b * 8);
            float4 h2A = hr2[0], h2B = hr2[1];
            uint32_t bn = ((uint32_t)m1.x >> 20) * 512 + (uint32_t)lane;
            uint32_t wn0 = wlds[bn],       wn1 = wlds[bn + 64];
            uint32_t wn2 = wlds[bn + 128], wn3 = wlds[bn + 192];
            uint32_t wn4 = wlds[bn + 256], wn5 = wlds[bn + 320];
            uint32_t wn6 = wlds[bn + 384], wn7 = wlds[bn + 448];

            uint32_t h01 = __builtin_bit_cast(uint32_t, __builtin_amdgcn_cvt_pkrtz(h0A.x, h0A.y));
            uint32_t h23 = __builtin_bit_cast(uint32_t, __builtin_amdgcn_cvt_pkrtz(h0A.z, h0A.w));
            uint32_t h45 = __builtin_bit_cast(uint32_t, __builtin_amdgcn_cvt_pkrtz(h0B.x, h0B.y));
            uint32_t h67 = __builtin_bit_cast(uint32_t, __builtin_amdgcn_cvt_pkrtz(h0B.z, h0B.w));

            float s0 = dot2f(h01, w0, 0.f);
            s0 = dot2f(h23, w2, s0);
            s0 = dot2f(h45, w4, s0);
            s0 = dot2f(h67, w6, s0);
            float s1 = dot2f(h01, w1, 0.f);
            s1 = dot2f(h23, w3, s1);
            s1 = dot2f(h45, w5, s1);
            s1 = dot2f(h67, w7, s1);

            const float nm = __int_as_float(m0.y);
            a0 = fmaf(s0, nm, a0);
            a1 = fmaf(s1, nm, a1);

            m0 = m1; m1 = m2; m2 = m3;
            h0A = h1A; h0B = h1B; h1A = h2A; h1B = h2B;
            w0 = wn0; w1 = wn1; w2 = wn2; w3 = wn3;
            w4 = wn4; w5 = wn5; w6 = wn6; w7 = wn7;
            ++j;
        }

        float2* op = reinterpret_cast<float2*>(out + (size_t)d * OUT_F + b * 8 + 2 * q);
        float2 bse = *op;
        float2 res;
        res.x = fmaxf(bse.x + a0, 0.f);
        res.y = fmaxf(bse.y + a1, 0.f);
        *op = res;
    }
}

extern "C" void kernel_launch(void* const* d_in, const int* in_sizes, int n_in,
                              void* d_out, int out_size, void* d_ws, size_t ws_size,
                              hipStream_t stream)
{
    const float* h      = (const float*)d_in[0];
    const float* norm   = (const float*)d_in[1];
    const float* weight = (const float*)d_in[2];
    const float* loop_w = (const float*)d_in[3];
    const float* bias   = (const float*)d_in[4];
    const int*   src    = (const int*)d_in[5];
    const int*   dst    = (const int*)d_in[6];
    const int*   rel    = (const int*)d_in[7];
    float* out = (float*)d_out;

    // ws layout: cnt[N], off[N+1], cur[N], part[512], wstart[N_WAVES+1],
    // wsw[64*512 u32], emeta[E+3] int2, h16[N*IN_F] fp16  -> ~35 MB
    char* wsb = (char*)d_ws;
    char* ws0 = wsb;
    int*  cnt    = (int*)wsb;  wsb += sizeof(int) * N_NODES;
    int*  off    = (int*)wsb;  wsb += sizeof(int) * (N_NODES + 1);
    int*  cur    = (int*)wsb;  wsb += sizeof(int) * N_NODES;
    int*  part   = (int*)wsb;  wsb += sizeof(int) * 512;
    int*  wstart = (int*)wsb;  wsb += sizeof(int) * (N_WAVES + 1);
    wsb = (char*)(((uintptr_t)wsb + 15) & ~(uintptr_t)15);
    uint32_t* wsw = (uint32_t*)wsb; wsb += sizeof(uint32_t) * NUM_RELS * 512;
    int2* emeta = (int2*)wsb;  wsb += sizeof(int2) * (N_EDGES + 3);
    wsb = (char*)(((uintptr_t)wsb + 15) & ~(uintptr_t)15);
    uint4* h16_4 = (uint4*)wsb; wsb += (size_t)N_NODES * IN_F * 2;

    const int use_h16 = (size_t)(wsb - ws0) <= ws_size;   // host-constant

    hipMemsetAsync(cnt, 0, sizeof(int) * N_NODES, stream);
    hipMemsetAsync(emeta + N_EDGES, 0, 3 * sizeof(int2), stream);   // pads

    const int h16_threads = use_h16 ? (N_NODES * IN_F / 8) : 0;
    const int ph_grid = (NUM_RELS * 512 + N_EDGES + h16_threads + 255) / 256;
    prep_hist_h16<<<ph_grid, 256, 0, stream>>>(weight, wsw, dst, cnt,
                                               h, h16_4, N_EDGES, use_h16);
    block_sums<<<NB_SCAN, 256, 0, stream>>>(cnt, part, N_NODES);
    scan_partials<<<1, 512, 0, stream>>>(part, NB_SCAN);
    write_off<<<NB_SCAN, 256, 0, stream>>>(cnt, part, off, cur, N_NODES, N_EDGES);
    const int fp_grid = (N_EDGES + N_WAVES + 1 + 255) / 256;
    fill_and_part<<<fp_grid, 256, 0, stream>>>(src, dst, rel, norm, cur, emeta,
                                               off, wstart, N_EDGES);

    gemm_selfloop<<<(N_NODES + 127) / 128, 256, 0, stream>>>(h, loop_w, bias, out, N_NODES);
    if (use_h16) {
        gather_nodes7<<<1024, 1024, 0, stream>>>(h16_4, wsw, off, emeta, wstart, out);
    } else {
        gather_nodes6<<<1024, 1024, 0, stream>>>(h, wsw, off, emeta, wstart, out);
    }
}